// Round 10
// baseline (991.975 us; speedup 1.0000x reference)
//
#include <hip/hip_runtime.h>
#include <hip/hip_fp16.h>
#include <math.h>

constexpr int N_NODES = 4096;
constexpr int N_EDGES = 65536;
constexpr int D_INF   = 64;
constexpr int H       = 128;
constexpr int T       = 8;
constexpr int B       = 8;
constexpr int M       = B * N_NODES;

typedef __attribute__((ext_vector_type(8))) short bf16x8;
typedef __attribute__((ext_vector_type(4))) float f32x4;
typedef __attribute__((ext_vector_type(8))) _Float16 f16x8;

__device__ inline unsigned short f2bf(float x) {
  unsigned int u = __float_as_uint(x);
  unsigned int r = (u + 0x7fffu + ((u >> 16) & 1u)) >> 16;
  return (unsigned short)r;
}
__device__ inline float bf2f(unsigned short b) {
  return __uint_as_float((unsigned int)b << 16);
}
// LDS bank swizzle: XOR byte bits 8-10 into bank bits 4-6 (short-index form).
__device__ __forceinline__ int swz(int s) { return s ^ (((s >> 7) & 7) << 3); }

// ---------------- CSR build ----------------

__global__ void k_count(const int* __restrict__ dst, int* __restrict__ cnt) {
  int e = blockIdx.x * blockDim.x + threadIdx.x;
  if (e < N_EDGES) atomicAdd(&cnt[dst[e]], 1);
}

__global__ void k_dinv(const int* __restrict__ cnt, float* __restrict__ dinv) {
  int n = blockIdx.x * blockDim.x + threadIdx.x;
  if (n < N_NODES) dinv[n] = 1.0f / sqrtf((float)cnt[n] + 2.0f);
}

__global__ void k_scan(const int* __restrict__ cnt, int* __restrict__ rowptr) {
  __shared__ int sums[1024];
  int t = threadIdx.x;
  int v0 = cnt[4*t+0], v1 = cnt[4*t+1], v2 = cnt[4*t+2], v3 = cnt[4*t+3];
  int s0 = v0, s1 = s0 + v1, s2 = s1 + v2, s3 = s2 + v3;
  sums[t] = s3;
  __syncthreads();
  for (int off = 1; off < 1024; off <<= 1) {
    int x = (t >= off) ? sums[t - off] : 0;
    __syncthreads();
    sums[t] += x;
    __syncthreads();
  }
  int base = (t > 0) ? sums[t - 1] : 0;
  if (t == 0) rowptr[0] = 0;
  rowptr[4*t+1] = base + s0;
  rowptr[4*t+2] = base + s1;
  rowptr[4*t+3] = base + s2;
  rowptr[4*t+4] = base + s3;
}

__global__ void k_fill(const int* __restrict__ src, const int* __restrict__ dst,
                       const float* __restrict__ dinv, const int* __restrict__ rowptr,
                       int* __restrict__ fill, int2* __restrict__ eg) {
  int e = blockIdx.x * blockDim.x + threadIdx.x;
  if (e >= N_EDGES) return;
  int s = src[e], d = dst[e];
  int p = rowptr[d] + atomicAdd(&fill[d], 1);
  eg[p] = make_int2(s, __float_as_int(dinv[s] * dinv[d]));
}

// ---------------- W pack: gate-interleaved cols + MFMA fragment order + hi/lo ----
__global__ void k_pack(const float* __restrict__ W, unsigned short* __restrict__ Bp,
                       int K) {
  int tid = blockIdx.x * 256 + threadIdx.x;
  if (tid >= K * 64) return;
  int lane = tid & 63;
  int ntg  = (tid >> 6) & 31;
  int kb   = tid >> 11;
  int gate = ntg & 3, fg = ntg >> 2;
  int corig = gate * 128 + fg * 16 + (lane & 15);
  int k0 = kb * 32 + (lane >> 4) * 8;
  long obase = ((long)(kb * 32 + ntg) * 64 + lane) * 8;
  long plane = (long)K * 512;
  #pragma unroll
  for (int j = 0; j < 8; ++j) {
    float v = W[(long)(k0 + j) * 512 + corig];
    unsigned short h = f2bf(v);
    Bp[obase + j]         = h;
    Bp[plane + obase + j] = f2bf(v - bf2f(h));
  }
}

// ---------------- fused: gather -> swizzled LDS fragments -> MFMA -> LSTM ----
// Block = 8 waves (512 thr) = 32 rows (one batch's 32 nodes) x all 512 gate cols.
// LDS 32/24 KB -> 4 blocks/CU = 32 waves/CU (max occupancy).
// Phase 1: 32 groups of 16 lanes; each group gathers ONE node's edges for BOTH
//   source planes (eg cached in L2 -- no NT), writes split-bf16 swizzled LDS.
// Phase 2: each wave computes ONE 16-feature group (all 4 gates, 32 rows).
template<int K, bool L0>
__global__ __launch_bounds__(512, 8) void k_fused(
    const int* __restrict__ rowptr, const int2* __restrict__ eg,
    const float* __restrict__ dinv,
    const float* __restrict__ X32,      // L0 only: x_t base (batch stride T*N*D)
    const _Float16* __restrict__ PH0,   // L0: h0_old ; L1: h0_new
    const _Float16* __restrict__ PH1,   // L1: h1_old
    const unsigned short* __restrict__ Bp, const float* __restrict__ bias,
    _Float16* __restrict__ hout, float* __restrict__ cbuf,
    float* __restrict__ out2, int t) {
  constexpr int KB = K / 32;
  __shared__ __align__(16) unsigned short At[4 * KB * 64 * 8];  // 24/32 KB
  int tid  = threadIdx.x;
  int lane = tid & 63;
  int w    = tid >> 6;                   // 0..7
  int j    = blockIdx.x;                 // 1024 blocks (1024%8==0, bijective)
  int b    = j & 7;                      // batch == XCD round-robin
  int n0   = (j >> 3) * 32;
  int m0   = b * N_NODES + n0;
  int g    = lane >> 4, l = lane & 15;
  int c4   = l * 4, c8 = l * 8;

  // ---- phase 1: gather both planes for one node per 16-lane group ----
  const float*    Ax   = L0 ? (X32 + (long)b * ((long)T * N_NODES * D_INF)) : nullptr;
  const _Float16* Ah_p = L0 ? nullptr : (PH0 + (long)b * N_NODES * H);
  const _Float16* Bh_p = (L0 ? PH0 : PH1) + (long)b * N_NODES * H;
  constexpr int kbB0 = (L0 ? 64 : 128) >> 5;
  int lane2f = 16 * (l & 3);
  int kbB    = kbB0 + (c8 >> 5);
  int kbA16  = c8 >> 5;
  int kbA32  = c4 >> 5;
  int subA32 = (l & 7) >> 1;
  int j0A32  = (l & 1) * 4;

  {
    int r  = (w << 2) + g;               // row in tile, 0..31
    int n  = n0 + r;
    int rs = rowptr[n], re = rowptr[n + 1];
    float accA[8] = {0.f,0.f,0.f,0.f,0.f,0.f,0.f,0.f};
    float accB[8] = {0.f,0.f,0.f,0.f,0.f,0.f,0.f,0.f};
    int e = rs;
    for (; e + 1 < re; e += 2) {
      int2 r0 = eg[e];
      int2 r1 = eg[e + 1];
      float w0 = __int_as_float(r0.y);
      float w1 = __int_as_float(r1.y);
      if constexpr (L0) {
        f32x4 a0 = *(const f32x4*)(Ax + (long)r0.x * D_INF + c4);
        f32x4 a1 = *(const f32x4*)(Ax + (long)r1.x * D_INF + c4);
        #pragma unroll
        for (int q = 0; q < 4; ++q) accA[q] += w0 * a0[q] + w1 * a1[q];
      } else {
        f16x8 a0 = *(const f16x8*)(Ah_p + (long)r0.x * H + c8);
        f16x8 a1 = *(const f16x8*)(Ah_p + (long)r1.x * H + c8);
        #pragma unroll
        for (int q = 0; q < 8; ++q) accA[q] += w0 * (float)a0[q] + w1 * (float)a1[q];
      }
      f16x8 b0 = *(const f16x8*)(Bh_p + (long)r0.x * H + c8);
      f16x8 b1 = *(const f16x8*)(Bh_p + (long)r1.x * H + c8);
      #pragma unroll
      for (int q = 0; q < 8; ++q) accB[q] += w0 * (float)b0[q] + w1 * (float)b1[q];
    }
    if (e < re) {
      int2 r0 = eg[e];
      float w0 = __int_as_float(r0.y);
      if constexpr (L0) {
        f32x4 a0 = *(const f32x4*)(Ax + (long)r0.x * D_INF + c4);
        #pragma unroll
        for (int q = 0; q < 4; ++q) accA[q] += w0 * a0[q];
      } else {
        f16x8 a0 = *(const f16x8*)(Ah_p + (long)r0.x * H + c8);
        #pragma unroll
        for (int q = 0; q < 8; ++q) accA[q] += w0 * (float)a0[q];
      }
      f16x8 b0 = *(const f16x8*)(Bh_p + (long)r0.x * H + c8);
      #pragma unroll
      for (int q = 0; q < 8; ++q) accB[q] += w0 * (float)b0[q];
    }
    float dn = dinv[n];
    float sw = 2.0f * dn * dn;
    if constexpr (L0) {
      f32x4 a = *(const f32x4*)(Ax + (long)n * D_INF + c4);
      #pragma unroll
      for (int q = 0; q < 4; ++q) accA[q] += sw * a[q];
    } else {
      f16x8 a = *(const f16x8*)(Ah_p + (long)n * H + c8);
      #pragma unroll
      for (int q = 0; q < 8; ++q) accA[q] += sw * (float)a[q];
    }
    {
      f16x8 v = *(const f16x8*)(Bh_p + (long)n * H + c8);
      #pragma unroll
      for (int q = 0; q < 8; ++q) accB[q] += sw * (float)v[q];
    }

    int mt    = r >> 4;                  // 0..1
    int lane2 = (r & 15) + lane2f;
    // plane B: full 8-feat chunk (hi plane pm=mt, lo plane pm=2+mt)
    {
      bf16x8 hv, lv;
      #pragma unroll
      for (int q = 0; q < 8; ++q) {
        unsigned short hs = f2bf(accB[q]);
        hv[q] = (short)hs;
        lv[q] = (short)f2bf(accB[q] - bf2f(hs));
      }
      *(bf16x8*)(At + swz((((mt)     * KB + kbB) * 64 + lane2) * 8)) = hv;
      *(bf16x8*)(At + swz((((2 + mt) * KB + kbB) * 64 + lane2) * 8)) = lv;
    }
    // plane A
    if constexpr (L0) {
      unsigned long long hv = 0ull, lv = 0ull;
      #pragma unroll
      for (int q = 0; q < 4; ++q) {
        unsigned short hs = f2bf(accA[q]);
        unsigned short ls = f2bf(accA[q] - bf2f(hs));
        hv |= (unsigned long long)hs << (16 * q);
        lv |= (unsigned long long)ls << (16 * q);
      }
      int lA = (r & 15) + 16 * subA32;
      *(unsigned long long*)(At + swz((((mt)     * KB + kbA32) * 64 + lA) * 8 + j0A32)) = hv;
      *(unsigned long long*)(At + swz((((2 + mt) * KB + kbA32) * 64 + lA) * 8 + j0A32)) = lv;
    } else {
      bf16x8 hv, lv;
      #pragma unroll
      for (int q = 0; q < 8; ++q) {
        unsigned short hs = f2bf(accA[q]);
        hv[q] = (short)hs;
        lv[q] = (short)f2bf(accA[q] - bf2f(hs));
      }
      *(bf16x8*)(At + swz((((mt)     * KB + kbA16) * 64 + lane2) * 8)) = hv;
      *(bf16x8*)(At + swz((((2 + mt) * KB + kbA16) * 64 + lane2) * 8)) = lv;
    }
  }
  __syncthreads();

  // ---- phase 2: split-bf16 3-term MFMA + LSTM epilogue (1 fg per wave) ----
  int l15 = lane & 15, lq = lane >> 4;
  const unsigned short* bb  = Bp + (long)(w * 4) * 512 + lane * 8;
  const unsigned short* blp = bb + (long)K * 512;

  f32x4 acc[2][4];
  #pragma unroll
  for (int mt = 0; mt < 2; ++mt)
    #pragma unroll
    for (int gt = 0; gt < 4; ++gt)
      acc[mt][gt] = (f32x4){0.f, 0.f, 0.f, 0.f};

  __builtin_amdgcn_s_setprio(1);
  for (int kb = 0; kb < KB; ++kb) {
    bf16x8 AH_[2], AL_[2];
    #pragma unroll
    for (int mt = 0; mt < 2; ++mt) {
      AH_[mt] = *(const bf16x8*)(At + swz((((mt)     * KB + kb) * 64 + lane) * 8));
      AL_[mt] = *(const bf16x8*)(At + swz((((2 + mt) * KB + kb) * 64 + lane) * 8));
    }
    bf16x8 BH[4], BL[4];
    #pragma unroll
    for (int gt = 0; gt < 4; ++gt) {
      BH[gt] = *(const bf16x8*)(bb  + ((long)kb * 32 + gt) * 512);
      BL[gt] = *(const bf16x8*)(blp + ((long)kb * 32 + gt) * 512);
    }
    #pragma unroll
    for (int gt = 0; gt < 4; ++gt) {
      #pragma unroll
      for (int mt = 0; mt < 2; ++mt) {
        acc[mt][gt] = __builtin_amdgcn_mfma_f32_16x16x32_bf16(AH_[mt], BH[gt], acc[mt][gt], 0, 0, 0);
        acc[mt][gt] = __builtin_amdgcn_mfma_f32_16x16x32_bf16(AL_[mt], BH[gt], acc[mt][gt], 0, 0, 0);
        acc[mt][gt] = __builtin_amdgcn_mfma_f32_16x16x32_bf16(AH_[mt], BL[gt], acc[mt][gt], 0, 0, 0);
      }
    }
  }
  __builtin_amdgcn_s_setprio(0);

  int f = w * 16 + l15;
  float bi = bias[f], bff = bias[128 + f], bo = bias[256 + f], bg = bias[384 + f];
  #pragma unroll
  for (int mt = 0; mt < 2; ++mt) {
    #pragma unroll
    for (int r = 0; r < 4; ++r) {
      int m = m0 + mt * 16 + lq * 4 + r;
      float vi = 1.0f / (1.0f + __expf(-(acc[mt][0][r] + bi)));
      float vf = 1.0f / (1.0f + __expf(-(acc[mt][1][r] + bff)));
      float vo = 1.0f / (1.0f + __expf(-(acc[mt][2][r] + bo)));
      float vg = tanhf(acc[mt][3][r] + bg);
      long idx = (long)m * H + f;
      float cn = vf * cbuf[idx] + vi * vg;
      float hn = vo * tanhf(cn);
      cbuf[idx] = cn;
      hout[idx] = (_Float16)hn;
      if (out2) {
        int bb2 = m >> 12, nn = m & (N_NODES - 1);
        __builtin_nontemporal_store(hn,
            &out2[(((long)bb2 * T + t) * N_NODES + nn) * H + f]);
      }
    }
  }
}

// ---------------- launch ----------------

extern "C" void kernel_launch(void* const* d_in, const int* in_sizes, int n_in,
                              void* d_out, int out_size, void* d_ws, size_t ws_size,
                              hipStream_t stream) {
  const float* x  = (const float*)d_in[0];
  const float* W0 = (const float*)d_in[1];
  const float* b0 = (const float*)d_in[2];
  const float* W1 = (const float*)d_in[3];
  const float* b1 = (const float*)d_in[4];
  const int*   ei = (const int*)d_in[5];
  const int* srcp = ei;
  const int* dstp = ei + N_EDGES;
  float* out = (float*)d_out;

  char* p = (char*)d_ws;
  auto alloc = [&](size_t bytes) {
    char* r = p;
    p += (bytes + 255) & ~(size_t)255;
    return r;
  };
  int*   cnt    = (int*)  alloc(N_NODES * 4);
  int*   fill   = (int*)  alloc(N_NODES * 4);
  float* dinv   = (float*)alloc(N_NODES * 4);
  int*   rowptr = (int*)  alloc((N_NODES + 1) * 4);
  int2*  eg     = (int2*) alloc((size_t)N_EDGES * 8);
  float* cc     = (float*)alloc((size_t)2 * M * H * 4);      // c0,c1 fp32
  _Float16* hh  = (_Float16*)alloc((size_t)4 * M * H * 2);   // h0 x2, h1 x2 (ping-pong)
  unsigned short* Bp0 = (unsigned short*)alloc((size_t)192 * 512 * 2 * 2);
  unsigned short* Bp1 = (unsigned short*)alloc((size_t)256 * 512 * 2 * 2);
  float*    c0  = cc;
  float*    c1  = cc + (size_t)M * H;
  _Float16* h0a = hh;
  _Float16* h0b = hh + (size_t)M * H;
  _Float16* h1a = hh + (size_t)2 * M * H;
  _Float16* h1b = hh + (size_t)3 * M * H;

  hipMemsetAsync(cnt,  0, N_NODES * 4, stream);
  hipMemsetAsync(fill, 0, N_NODES * 4, stream);
  hipMemsetAsync(cc,   0, (size_t)2 * M * H * 4, stream);
  hipMemsetAsync(hh,   0, (size_t)4 * M * H * 2, stream);

  k_count<<<N_EDGES / 256, 256, 0, stream>>>(dstp, cnt);
  k_dinv <<<N_NODES / 256, 256, 0, stream>>>(cnt, dinv);
  k_scan <<<1, 1024, 0, stream>>>(cnt, rowptr);
  k_fill <<<N_EDGES / 256, 256, 0, stream>>>(srcp, dstp, dinv, rowptr, fill, eg);
  k_pack <<<(192 * 64 + 255) / 256, 256, 0, stream>>>(W0, Bp0, 192);
  k_pack <<<(256 * 64 + 255) / 256, 256, 0, stream>>>(W1, Bp1, 256);

  for (int t = 0; t < T; ++t) {
    const _Float16* h0r = (t & 1) ? h0b : h0a;
    _Float16*       h0w = (t & 1) ? h0a : h0b;
    const _Float16* h1r = (t & 1) ? h1b : h1a;
    _Float16*       h1w = (t & 1) ? h1a : h1b;
    // layer 0: gather [x_t | h0_old] -> gates -> h0_new, c0
    k_fused<192, true><<<1024, 512, 0, stream>>>(rowptr, eg, dinv,
        x + (size_t)t * N_NODES * D_INF, h0r, nullptr,
        Bp0, b0, h0w, c0, nullptr, t);
    // layer 1: gather [h0_new | h1_old] -> gates -> h1_new, c1, out
    k_fused<256, false><<<1024, 512, 0, stream>>>(rowptr, eg, dinv,
        nullptr, h0w, h1r,
        Bp1, b1, h1w, c1, out, t);
  }
}

// Round 11
// 925.892 us; speedup vs baseline: 1.0714x; 1.0714x over previous
//
#include <hip/hip_runtime.h>
#include <hip/hip_fp16.h>
#include <math.h>

constexpr int N_NODES = 4096;
constexpr int N_EDGES = 65536;
constexpr int D_INF   = 64;
constexpr int H       = 128;
constexpr int T       = 8;
constexpr int B       = 8;
constexpr int M       = B * N_NODES;

typedef __attribute__((ext_vector_type(8))) short bf16x8;
typedef __attribute__((ext_vector_type(4))) float f32x4;
typedef __attribute__((ext_vector_type(8))) _Float16 f16x8;

__device__ inline unsigned short f2bf(float x) {
  unsigned int u = __float_as_uint(x);
  unsigned int r = (u + 0x7fffu + ((u >> 16) & 1u)) >> 16;
  return (unsigned short)r;
}
__device__ inline float bf2f(unsigned short b) {
  return __uint_as_float((unsigned int)b << 16);
}
// LDS bank swizzle: XOR byte bits 8-10 into bank bits 4-6 (short-index form).
__device__ __forceinline__ int swz(int s) { return s ^ (((s >> 7) & 7) << 3); }

// ---------------- CSR build ----------------

__global__ void k_count(const int* __restrict__ dst, int* __restrict__ cnt) {
  int e = blockIdx.x * blockDim.x + threadIdx.x;
  if (e < N_EDGES) atomicAdd(&cnt[dst[e]], 1);
}

__global__ void k_dinv(const int* __restrict__ cnt, float* __restrict__ dinv) {
  int n = blockIdx.x * blockDim.x + threadIdx.x;
  if (n < N_NODES) dinv[n] = 1.0f / sqrtf((float)cnt[n] + 2.0f);
}

__global__ void k_scan(const int* __restrict__ cnt, int* __restrict__ rowptr) {
  __shared__ int sums[1024];
  int t = threadIdx.x;
  int v0 = cnt[4*t+0], v1 = cnt[4*t+1], v2 = cnt[4*t+2], v3 = cnt[4*t+3];
  int s0 = v0, s1 = s0 + v1, s2 = s1 + v2, s3 = s2 + v3;
  sums[t] = s3;
  __syncthreads();
  for (int off = 1; off < 1024; off <<= 1) {
    int x = (t >= off) ? sums[t - off] : 0;
    __syncthreads();
    sums[t] += x;
    __syncthreads();
  }
  int base = (t > 0) ? sums[t - 1] : 0;
  if (t == 0) rowptr[0] = 0;
  rowptr[4*t+1] = base + s0;
  rowptr[4*t+2] = base + s1;
  rowptr[4*t+3] = base + s2;
  rowptr[4*t+4] = base + s3;
}

__global__ void k_fill(const int* __restrict__ src, const int* __restrict__ dst,
                       const float* __restrict__ dinv, const int* __restrict__ rowptr,
                       int* __restrict__ fill, int2* __restrict__ eg) {
  int e = blockIdx.x * blockDim.x + threadIdx.x;
  if (e >= N_EDGES) return;
  int s = src[e], d = dst[e];
  int p = rowptr[d] + atomicAdd(&fill[d], 1);
  eg[p] = make_int2(s, __float_as_int(dinv[s] * dinv[d]));
}

// ---------------- W pack: gate-interleaved cols + MFMA fragment order + hi/lo ----
__global__ void k_pack(const float* __restrict__ W, unsigned short* __restrict__ Bp,
                       int K) {
  int tid = blockIdx.x * 256 + threadIdx.x;
  if (tid >= K * 64) return;
  int lane = tid & 63;
  int ntg  = (tid >> 6) & 31;
  int kb   = tid >> 11;
  int gate = ntg & 3, fg = ntg >> 2;
  int corig = gate * 128 + fg * 16 + (lane & 15);
  int k0 = kb * 32 + (lane >> 4) * 8;
  long obase = ((long)(kb * 32 + ntg) * 64 + lane) * 8;
  long plane = (long)K * 512;
  #pragma unroll
  for (int j = 0; j < 8; ++j) {
    float v = W[(long)(k0 + j) * 512 + corig];
    unsigned short h = f2bf(v);
    Bp[obase + j]         = h;
    Bp[plane + obase + j] = f2bf(v - bf2f(h));
  }
}

// ---------------- fused: gather -> swizzled LDS fragments -> MFMA -> LSTM ----
// Block = 8 waves (512 thr) = 32 rows (one batch's 32 nodes) x all 512 gate cols.
// LDS 24/32 KB. __launch_bounds__(512,6): VGPR cap ~85 -> NO SPILL (round 10's
// (512,8) cap forced 32 VGPR and ~90 MB/dispatch of scratch traffic).
// 3 blocks/CU = 24 waves/CU.
template<int K, bool L0>
__global__ __launch_bounds__(512, 6) void k_fused(
    const int* __restrict__ rowptr, const int2* __restrict__ eg,
    const float* __restrict__ dinv,
    const float* __restrict__ X32,      // L0 only: x_t base (batch stride T*N*D)
    const _Float16* __restrict__ PH0,   // L0: h0_old ; L1: h0_new
    const _Float16* __restrict__ PH1,   // L1: h1_old
    const unsigned short* __restrict__ Bp, const float* __restrict__ bias,
    _Float16* __restrict__ hout, float* __restrict__ cbuf,
    float* __restrict__ out2, int t) {
  constexpr int KB = K / 32;
  __shared__ __align__(16) unsigned short At[4 * KB * 64 * 8];  // 24/32 KB
  int tid  = threadIdx.x;
  int lane = tid & 63;
  int w    = tid >> 6;                   // 0..7
  int j    = blockIdx.x;                 // 1024 blocks (1024%8==0, bijective)
  int b    = j & 7;                      // batch == XCD round-robin
  int n0   = (j >> 3) * 32;
  int m0   = b * N_NODES + n0;
  int g    = lane >> 4, l = lane & 15;
  int c4   = l * 4, c8 = l * 8;

  // ---- phase 1: gather both planes for one node per 16-lane group ----
  const float*    Ax   = L0 ? (X32 + (long)b * ((long)T * N_NODES * D_INF)) : nullptr;
  const _Float16* Ah_p = L0 ? nullptr : (PH0 + (long)b * N_NODES * H);
  const _Float16* Bh_p = (L0 ? PH0 : PH1) + (long)b * N_NODES * H;
  constexpr int kbB0 = (L0 ? 64 : 128) >> 5;
  int lane2f = 16 * (l & 3);
  int kbB    = kbB0 + (c8 >> 5);
  int kbA16  = c8 >> 5;
  int kbA32  = c4 >> 5;
  int subA32 = (l & 7) >> 1;
  int j0A32  = (l & 1) * 4;

  {
    int r  = (w << 2) + g;               // row in tile, 0..31
    int n  = n0 + r;
    int rs = rowptr[n], re = rowptr[n + 1];
    float accA[8] = {0.f,0.f,0.f,0.f,0.f,0.f,0.f,0.f};
    float accB[8] = {0.f,0.f,0.f,0.f,0.f,0.f,0.f,0.f};
    int e = rs;
    for (; e + 1 < re; e += 2) {
      int2 r0 = eg[e];
      int2 r1 = eg[e + 1];
      float w0 = __int_as_float(r0.y);
      float w1 = __int_as_float(r1.y);
      if constexpr (L0) {
        f32x4 a0 = *(const f32x4*)(Ax + (long)r0.x * D_INF + c4);
        f32x4 a1 = *(const f32x4*)(Ax + (long)r1.x * D_INF + c4);
        #pragma unroll
        for (int q = 0; q < 4; ++q) accA[q] += w0 * a0[q] + w1 * a1[q];
      } else {
        f16x8 a0 = *(const f16x8*)(Ah_p + (long)r0.x * H + c8);
        f16x8 a1 = *(const f16x8*)(Ah_p + (long)r1.x * H + c8);
        #pragma unroll
        for (int q = 0; q < 8; ++q) accA[q] += w0 * (float)a0[q] + w1 * (float)a1[q];
      }
      f16x8 b0 = *(const f16x8*)(Bh_p + (long)r0.x * H + c8);
      f16x8 b1 = *(const f16x8*)(Bh_p + (long)r1.x * H + c8);
      #pragma unroll
      for (int q = 0; q < 8; ++q) accB[q] += w0 * (float)b0[q] + w1 * (float)b1[q];
    }
    if (e < re) {
      int2 r0 = eg[e];
      float w0 = __int_as_float(r0.y);
      if constexpr (L0) {
        f32x4 a0 = *(const f32x4*)(Ax + (long)r0.x * D_INF + c4);
        #pragma unroll
        for (int q = 0; q < 4; ++q) accA[q] += w0 * a0[q];
      } else {
        f16x8 a0 = *(const f16x8*)(Ah_p + (long)r0.x * H + c8);
        #pragma unroll
        for (int q = 0; q < 8; ++q) accA[q] += w0 * (float)a0[q];
      }
      f16x8 b0 = *(const f16x8*)(Bh_p + (long)r0.x * H + c8);
      #pragma unroll
      for (int q = 0; q < 8; ++q) accB[q] += w0 * (float)b0[q];
    }
    float dn = dinv[n];
    float sw = 2.0f * dn * dn;
    if constexpr (L0) {
      f32x4 a = *(const f32x4*)(Ax + (long)n * D_INF + c4);
      #pragma unroll
      for (int q = 0; q < 4; ++q) accA[q] += sw * a[q];
    } else {
      f16x8 a = *(const f16x8*)(Ah_p + (long)n * H + c8);
      #pragma unroll
      for (int q = 0; q < 8; ++q) accA[q] += sw * (float)a[q];
    }
    {
      f16x8 v = *(const f16x8*)(Bh_p + (long)n * H + c8);
      #pragma unroll
      for (int q = 0; q < 8; ++q) accB[q] += sw * (float)v[q];
    }

    int mt    = r >> 4;                  // 0..1
    int lane2 = (r & 15) + lane2f;
    // plane B: full 8-feat chunk (hi plane pm=mt, lo plane pm=2+mt)
    {
      bf16x8 hv, lv;
      #pragma unroll
      for (int q = 0; q < 8; ++q) {
        unsigned short hs = f2bf(accB[q]);
        hv[q] = (short)hs;
        lv[q] = (short)f2bf(accB[q] - bf2f(hs));
      }
      *(bf16x8*)(At + swz((((mt)     * KB + kbB) * 64 + lane2) * 8)) = hv;
      *(bf16x8*)(At + swz((((2 + mt) * KB + kbB) * 64 + lane2) * 8)) = lv;
    }
    // plane A
    if constexpr (L0) {
      unsigned long long hv = 0ull, lv = 0ull;
      #pragma unroll
      for (int q = 0; q < 4; ++q) {
        unsigned short hs = f2bf(accA[q]);
        unsigned short ls = f2bf(accA[q] - bf2f(hs));
        hv |= (unsigned long long)hs << (16 * q);
        lv |= (unsigned long long)ls << (16 * q);
      }
      int lA = (r & 15) + 16 * subA32;
      *(unsigned long long*)(At + swz((((mt)     * KB + kbA32) * 64 + lA) * 8 + j0A32)) = hv;
      *(unsigned long long*)(At + swz((((2 + mt) * KB + kbA32) * 64 + lA) * 8 + j0A32)) = lv;
    } else {
      bf16x8 hv, lv;
      #pragma unroll
      for (int q = 0; q < 8; ++q) {
        unsigned short hs = f2bf(accA[q]);
        hv[q] = (short)hs;
        lv[q] = (short)f2bf(accA[q] - bf2f(hs));
      }
      *(bf16x8*)(At + swz((((mt)     * KB + kbA16) * 64 + lane2) * 8)) = hv;
      *(bf16x8*)(At + swz((((2 + mt) * KB + kbA16) * 64 + lane2) * 8)) = lv;
    }
  }
  __syncthreads();

  // ---- phase 2: split-bf16 3-term MFMA + LSTM epilogue (1 fg per wave) ----
  int l15 = lane & 15, lq = lane >> 4;
  const unsigned short* bb  = Bp + (long)(w * 4) * 512 + lane * 8;
  const unsigned short* blp = bb + (long)K * 512;

  f32x4 acc[2][4];
  #pragma unroll
  for (int mt = 0; mt < 2; ++mt)
    #pragma unroll
    for (int gt = 0; gt < 4; ++gt)
      acc[mt][gt] = (f32x4){0.f, 0.f, 0.f, 0.f};

  __builtin_amdgcn_s_setprio(1);
  for (int kb = 0; kb < KB; ++kb) {
    bf16x8 AH_[2], AL_[2];
    #pragma unroll
    for (int mt = 0; mt < 2; ++mt) {
      AH_[mt] = *(const bf16x8*)(At + swz((((mt)     * KB + kb) * 64 + lane) * 8));
      AL_[mt] = *(const bf16x8*)(At + swz((((2 + mt) * KB + kb) * 64 + lane) * 8));
    }
    bf16x8 BH[4], BL[4];
    #pragma unroll
    for (int gt = 0; gt < 4; ++gt) {
      BH[gt] = *(const bf16x8*)(bb  + ((long)kb * 32 + gt) * 512);
      BL[gt] = *(const bf16x8*)(blp + ((long)kb * 32 + gt) * 512);
    }
    #pragma unroll
    for (int gt = 0; gt < 4; ++gt) {
      #pragma unroll
      for (int mt = 0; mt < 2; ++mt) {
        acc[mt][gt] = __builtin_amdgcn_mfma_f32_16x16x32_bf16(AH_[mt], BH[gt], acc[mt][gt], 0, 0, 0);
        acc[mt][gt] = __builtin_amdgcn_mfma_f32_16x16x32_bf16(AL_[mt], BH[gt], acc[mt][gt], 0, 0, 0);
        acc[mt][gt] = __builtin_amdgcn_mfma_f32_16x16x32_bf16(AH_[mt], BL[gt], acc[mt][gt], 0, 0, 0);
      }
    }
  }
  __builtin_amdgcn_s_setprio(0);

  int f = w * 16 + l15;
  float bi = bias[f], bff = bias[128 + f], bo = bias[256 + f], bg = bias[384 + f];
  #pragma unroll
  for (int mt = 0; mt < 2; ++mt) {
    #pragma unroll
    for (int r = 0; r < 4; ++r) {
      int m = m0 + mt * 16 + lq * 4 + r;
      float vi = 1.0f / (1.0f + __expf(-(acc[mt][0][r] + bi)));
      float vf = 1.0f / (1.0f + __expf(-(acc[mt][1][r] + bff)));
      float vo = 1.0f / (1.0f + __expf(-(acc[mt][2][r] + bo)));
      float vg = tanhf(acc[mt][3][r] + bg);
      long idx = (long)m * H + f;
      float cn = vf * cbuf[idx] + vi * vg;
      float hn = vo * tanhf(cn);
      cbuf[idx] = cn;
      hout[idx] = (_Float16)hn;
      if (out2) {
        int bb2 = m >> 12, nn = m & (N_NODES - 1);
        __builtin_nontemporal_store(hn,
            &out2[(((long)bb2 * T + t) * N_NODES + nn) * H + f]);
      }
    }
  }
}

// ---------------- launch ----------------

extern "C" void kernel_launch(void* const* d_in, const int* in_sizes, int n_in,
                              void* d_out, int out_size, void* d_ws, size_t ws_size,
                              hipStream_t stream) {
  const float* x  = (const float*)d_in[0];
  const float* W0 = (const float*)d_in[1];
  const float* b0 = (const float*)d_in[2];
  const float* W1 = (const float*)d_in[3];
  const float* b1 = (const float*)d_in[4];
  const int*   ei = (const int*)d_in[5];
  const int* srcp = ei;
  const int* dstp = ei + N_EDGES;
  float* out = (float*)d_out;

  char* p = (char*)d_ws;
  auto alloc = [&](size_t bytes) {
    char* r = p;
    p += (bytes + 255) & ~(size_t)255;
    return r;
  };
  int*   cnt    = (int*)  alloc(N_NODES * 4);
  int*   fill   = (int*)  alloc(N_NODES * 4);
  float* dinv   = (float*)alloc(N_NODES * 4);
  int*   rowptr = (int*)  alloc((N_NODES + 1) * 4);
  int2*  eg     = (int2*) alloc((size_t)N_EDGES * 8);
  float* cc     = (float*)alloc((size_t)2 * M * H * 4);      // c0,c1 fp32
  _Float16* hh  = (_Float16*)alloc((size_t)4 * M * H * 2);   // h0 x2, h1 x2 (ping-pong)
  unsigned short* Bp0 = (unsigned short*)alloc((size_t)192 * 512 * 2 * 2);
  unsigned short* Bp1 = (unsigned short*)alloc((size_t)256 * 512 * 2 * 2);
  float*    c0  = cc;
  float*    c1  = cc + (size_t)M * H;
  _Float16* h0a = hh;
  _Float16* h0b = hh + (size_t)M * H;
  _Float16* h1a = hh + (size_t)2 * M * H;
  _Float16* h1b = hh + (size_t)3 * M * H;

  hipMemsetAsync(cnt,  0, N_NODES * 4, stream);
  hipMemsetAsync(fill, 0, N_NODES * 4, stream);
  hipMemsetAsync(cc,   0, (size_t)2 * M * H * 4, stream);
  hipMemsetAsync(hh,   0, (size_t)4 * M * H * 2, stream);

  k_count<<<N_EDGES / 256, 256, 0, stream>>>(dstp, cnt);
  k_dinv <<<N_NODES / 256, 256, 0, stream>>>(cnt, dinv);
  k_scan <<<1, 1024, 0, stream>>>(cnt, rowptr);
  k_fill <<<N_EDGES / 256, 256, 0, stream>>>(srcp, dstp, dinv, rowptr, fill, eg);
  k_pack <<<(192 * 64 + 255) / 256, 256, 0, stream>>>(W0, Bp0, 192);
  k_pack <<<(256 * 64 + 255) / 256, 256, 0, stream>>>(W1, Bp1, 256);

  for (int t = 0; t < T; ++t) {
    const _Float16* h0r = (t & 1) ? h0b : h0a;
    _Float16*       h0w = (t & 1) ? h0a : h0b;
    const _Float16* h1r = (t & 1) ? h1b : h1a;
    _Float16*       h1w = (t & 1) ? h1a : h1b;
    // layer 0: gather [x_t | h0_old] -> gates -> h0_new, c0
    k_fused<192, true><<<1024, 512, 0, stream>>>(rowptr, eg, dinv,
        x + (size_t)t * N_NODES * D_INF, h0r, nullptr,
        Bp0, b0, h0w, c0, nullptr, t);
    // layer 1: gather [h0_new | h1_old] -> gates -> h1_new, c1, out
    k_fused<256, false><<<1024, 512, 0, stream>>>(rowptr, eg, dinv,
        nullptr, h0w, h1r,
        Bp1, b1, h1w, c1, out, t);
  }
}

// Round 12
// 795.948 us; speedup vs baseline: 1.2463x; 1.1633x over previous
//
#include <hip/hip_runtime.h>
#include <hip/hip_fp16.h>
#include <math.h>

constexpr int N_NODES = 4096;
constexpr int N_EDGES = 65536;
constexpr int D_INF   = 64;
constexpr int H       = 128;
constexpr int T       = 8;
constexpr int B       = 8;
constexpr int M       = B * N_NODES;

typedef __attribute__((ext_vector_type(8))) short bf16x8;
typedef __attribute__((ext_vector_type(4))) float f32x4;
typedef __attribute__((ext_vector_type(8))) _Float16 f16x8;

__device__ inline unsigned short f2bf(float x) {
  unsigned int u = __float_as_uint(x);
  unsigned int r = (u + 0x7fffu + ((u >> 16) & 1u)) >> 16;
  return (unsigned short)r;
}
__device__ inline float bf2f(unsigned short b) {
  return __uint_as_float((unsigned int)b << 16);
}
// LDS bank swizzle: XOR short-index bits 7-9 into bits 3-5 (bank bits).
__device__ __forceinline__ int swz(int s) { return s ^ (((s >> 7) & 7) << 3); }

// ---------------- CSR build ----------------

__global__ void k_count(const int* __restrict__ dst, int* __restrict__ cnt) {
  int e = blockIdx.x * blockDim.x + threadIdx.x;
  if (e < N_EDGES) atomicAdd(&cnt[dst[e]], 1);
}

__global__ void k_dinv(const int* __restrict__ cnt, float* __restrict__ dinv) {
  int n = blockIdx.x * blockDim.x + threadIdx.x;
  if (n < N_NODES) dinv[n] = 1.0f / sqrtf((float)cnt[n] + 2.0f);
}

__global__ void k_scan(const int* __restrict__ cnt, int* __restrict__ rowptr) {
  __shared__ int sums[1024];
  int t = threadIdx.x;
  int v0 = cnt[4*t+0], v1 = cnt[4*t+1], v2 = cnt[4*t+2], v3 = cnt[4*t+3];
  int s0 = v0, s1 = s0 + v1, s2 = s1 + v2, s3 = s2 + v3;
  sums[t] = s3;
  __syncthreads();
  for (int off = 1; off < 1024; off <<= 1) {
    int x = (t >= off) ? sums[t - off] : 0;
    __syncthreads();
    sums[t] += x;
    __syncthreads();
  }
  int base = (t > 0) ? sums[t - 1] : 0;
  if (t == 0) rowptr[0] = 0;
  rowptr[4*t+1] = base + s0;
  rowptr[4*t+2] = base + s1;
  rowptr[4*t+3] = base + s2;
  rowptr[4*t+4] = base + s3;
}

__global__ void k_fill(const int* __restrict__ src, const int* __restrict__ dst,
                       const float* __restrict__ dinv, const int* __restrict__ rowptr,
                       int* __restrict__ fill, int2* __restrict__ eg) {
  int e = blockIdx.x * blockDim.x + threadIdx.x;
  if (e >= N_EDGES) return;
  int s = src[e], d = dst[e];
  int p = rowptr[d] + atomicAdd(&fill[d], 1);
  eg[p] = make_int2(s, __float_as_int(dinv[s] * dinv[d]));
}

// ---------------- W pack: gate-interleaved cols + MFMA fragment order + hi/lo ----
__global__ void k_pack(const float* __restrict__ W, unsigned short* __restrict__ Bp,
                       int K) {
  int tid = blockIdx.x * 256 + threadIdx.x;
  if (tid >= K * 64) return;
  int lane = tid & 63;
  int ntg  = (tid >> 6) & 31;
  int kb   = tid >> 11;
  int gate = ntg & 3, fg = ntg >> 2;
  int corig = gate * 128 + fg * 16 + (lane & 15);
  int k0 = kb * 32 + (lane >> 4) * 8;
  long obase = ((long)(kb * 32 + ntg) * 64 + lane) * 8;
  long plane = (long)K * 512;
  #pragma unroll
  for (int j = 0; j < 8; ++j) {
    float v = W[(long)(k0 + j) * 512 + corig];
    unsigned short h = f2bf(v);
    Bp[obase + j]         = h;
    Bp[plane + obase + j] = f2bf(v - bf2f(h));
  }
}

// ---------------- fused: gather -> swizzled LDS fragments -> MFMA -> LSTM ----
// Block = 8 waves (512 thr) = 64 rows (one batch's 64 nodes) x all 512 gate cols.
// LDS 48/64 KB -> 2 blocks/CU; (512,4) caps VGPR at 128 (no spill).
// Phase 1: 32 groups of 16 lanes; each group gathers 2 nodes, 4-edge software
//   pipeline (8 concurrent gathers) to cut the dependent-latency chain ~2x.
// Phase 2: each wave computes ONE 16-feature group (all 4 gates, 64 rows),
//   kb-loop unrolled 2x so next-kb B loads issue under current MFMAs.
template<int K, bool L0>
__global__ __launch_bounds__(512, 4) void k_fused(
    const int* __restrict__ rowptr, const int2* __restrict__ eg,
    const float* __restrict__ dinv,
    const float* __restrict__ X32,      // L0 only: x_t base (batch stride T*N*D)
    const _Float16* __restrict__ PH0,   // L0: h0_old ; L1: h0_new
    const _Float16* __restrict__ PH1,   // L1: h1_old
    const unsigned short* __restrict__ Bp, const float* __restrict__ bias,
    _Float16* __restrict__ hout, float* __restrict__ cbuf,
    float* __restrict__ out2, int t) {
  constexpr int KB = K / 32;
  __shared__ __align__(16) unsigned short At[8 * KB * 64 * 8];  // 48/64 KB
  int tid  = threadIdx.x;
  int lane = tid & 63;
  int w    = tid >> 6;                   // 0..7
  int j    = blockIdx.x;                 // 512 blocks (512%8==0, bijective)
  int b    = j & 7;                      // batch == XCD round-robin
  int n0   = (j >> 3) * 64;
  int m0   = b * N_NODES + n0;
  int g    = lane >> 4, l = lane & 15;
  int c4   = l * 4, c8 = l * 8;

  // ---- phase 1: gather both planes, 2 nodes per 16-lane group ----
  const float*    Ax   = L0 ? (X32 + (long)b * ((long)T * N_NODES * D_INF)) : nullptr;
  const _Float16* Ah_p = L0 ? nullptr : (PH0 + (long)b * N_NODES * H);
  const _Float16* Bh_p = (L0 ? PH0 : PH1) + (long)b * N_NODES * H;
  constexpr int kbB0 = (L0 ? 64 : 128) >> 5;
  int lane2f = 16 * (l & 3);
  int kbB    = kbB0 + (c8 >> 5);
  int kbA16  = c8 >> 5;
  int kbA32  = c4 >> 5;
  int subA32 = (l & 7) >> 1;
  int j0A32  = (l & 1) * 4;

  #pragma unroll
  for (int nd = 0; nd < 2; ++nd) {
    int r  = (w << 3) + (g << 1) + nd;   // row in tile, 0..63
    int n  = n0 + r;
    int rs = rowptr[n], re = rowptr[n + 1];
    float accA[8] = {0.f,0.f,0.f,0.f,0.f,0.f,0.f,0.f};
    float accB[8] = {0.f,0.f,0.f,0.f,0.f,0.f,0.f,0.f};
    int e = rs;
    // 4-edge software pipeline: 4 metadata loads + 8 concurrent gathers
    for (; e + 3 < re; e += 4) {
      int2 q0 = eg[e], q1 = eg[e + 1], q2 = eg[e + 2], q3 = eg[e + 3];
      float w0 = __int_as_float(q0.y), w1 = __int_as_float(q1.y);
      float w2 = __int_as_float(q2.y), w3 = __int_as_float(q3.y);
      if constexpr (L0) {
        f32x4 a0 = *(const f32x4*)(Ax + (long)q0.x * D_INF + c4);
        f32x4 a1 = *(const f32x4*)(Ax + (long)q1.x * D_INF + c4);
        f32x4 a2 = *(const f32x4*)(Ax + (long)q2.x * D_INF + c4);
        f32x4 a3 = *(const f32x4*)(Ax + (long)q3.x * D_INF + c4);
        #pragma unroll
        for (int q = 0; q < 4; ++q)
          accA[q] += w0 * a0[q] + w1 * a1[q] + w2 * a2[q] + w3 * a3[q];
      } else {
        f16x8 a0 = *(const f16x8*)(Ah_p + (long)q0.x * H + c8);
        f16x8 a1 = *(const f16x8*)(Ah_p + (long)q1.x * H + c8);
        f16x8 a2 = *(const f16x8*)(Ah_p + (long)q2.x * H + c8);
        f16x8 a3 = *(const f16x8*)(Ah_p + (long)q3.x * H + c8);
        #pragma unroll
        for (int q = 0; q < 8; ++q)
          accA[q] += w0 * (float)a0[q] + w1 * (float)a1[q]
                   + w2 * (float)a2[q] + w3 * (float)a3[q];
      }
      f16x8 b0 = *(const f16x8*)(Bh_p + (long)q0.x * H + c8);
      f16x8 b1 = *(const f16x8*)(Bh_p + (long)q1.x * H + c8);
      f16x8 b2 = *(const f16x8*)(Bh_p + (long)q2.x * H + c8);
      f16x8 b3 = *(const f16x8*)(Bh_p + (long)q3.x * H + c8);
      #pragma unroll
      for (int q = 0; q < 8; ++q)
        accB[q] += w0 * (float)b0[q] + w1 * (float)b1[q]
                 + w2 * (float)b2[q] + w3 * (float)b3[q];
    }
    for (; e < re; ++e) {
      int2 q0 = eg[e];
      float w0 = __int_as_float(q0.y);
      if constexpr (L0) {
        f32x4 a0 = *(const f32x4*)(Ax + (long)q0.x * D_INF + c4);
        #pragma unroll
        for (int q = 0; q < 4; ++q) accA[q] += w0 * a0[q];
      } else {
        f16x8 a0 = *(const f16x8*)(Ah_p + (long)q0.x * H + c8);
        #pragma unroll
        for (int q = 0; q < 8; ++q) accA[q] += w0 * (float)a0[q];
      }
      f16x8 b0 = *(const f16x8*)(Bh_p + (long)q0.x * H + c8);
      #pragma unroll
      for (int q = 0; q < 8; ++q) accB[q] += w0 * (float)b0[q];
    }
    float dn = dinv[n];
    float sw = 2.0f * dn * dn;
    if constexpr (L0) {
      f32x4 a = *(const f32x4*)(Ax + (long)n * D_INF + c4);
      #pragma unroll
      for (int q = 0; q < 4; ++q) accA[q] += sw * a[q];
    } else {
      f16x8 a = *(const f16x8*)(Ah_p + (long)n * H + c8);
      #pragma unroll
      for (int q = 0; q < 8; ++q) accA[q] += sw * (float)a[q];
    }
    {
      f16x8 v = *(const f16x8*)(Bh_p + (long)n * H + c8);
      #pragma unroll
      for (int q = 0; q < 8; ++q) accB[q] += sw * (float)v[q];
    }

    int mt    = r >> 4;                  // 0..3
    int lane2 = (r & 15) + lane2f;
    // plane B: full 8-feat chunk (hi pm=mt, lo pm=4+mt)
    {
      bf16x8 hv, lv;
      #pragma unroll
      for (int q = 0; q < 8; ++q) {
        unsigned short hs = f2bf(accB[q]);
        hv[q] = (short)hs;
        lv[q] = (short)f2bf(accB[q] - bf2f(hs));
      }
      *(bf16x8*)(At + swz((((mt)     * KB + kbB) * 64 + lane2) * 8)) = hv;
      *(bf16x8*)(At + swz((((4 + mt) * KB + kbB) * 64 + lane2) * 8)) = lv;
    }
    // plane A
    if constexpr (L0) {
      unsigned long long hv = 0ull, lv = 0ull;
      #pragma unroll
      for (int q = 0; q < 4; ++q) {
        unsigned short hs = f2bf(accA[q]);
        unsigned short ls = f2bf(accA[q] - bf2f(hs));
        hv |= (unsigned long long)hs << (16 * q);
        lv |= (unsigned long long)ls << (16 * q);
      }
      int lA = (r & 15) + 16 * subA32;
      *(unsigned long long*)(At + swz((((mt)     * KB + kbA32) * 64 + lA) * 8 + j0A32)) = hv;
      *(unsigned long long*)(At + swz((((4 + mt) * KB + kbA32) * 64 + lA) * 8 + j0A32)) = lv;
    } else {
      bf16x8 hv, lv;
      #pragma unroll
      for (int q = 0; q < 8; ++q) {
        unsigned short hs = f2bf(accA[q]);
        hv[q] = (short)hs;
        lv[q] = (short)f2bf(accA[q] - bf2f(hs));
      }
      *(bf16x8*)(At + swz((((mt)     * KB + kbA16) * 64 + lane2) * 8)) = hv;
      *(bf16x8*)(At + swz((((4 + mt) * KB + kbA16) * 64 + lane2) * 8)) = lv;
    }
  }
  __syncthreads();

  // ---- phase 2: split-bf16 3-term MFMA + LSTM epilogue (1 fg per wave) ----
  int l15 = lane & 15, lq = lane >> 4;
  const unsigned short* bb  = Bp + (long)(w * 4) * 512 + lane * 8;
  const unsigned short* blp = bb + (long)K * 512;

  f32x4 acc[4][4];
  #pragma unroll
  for (int mt = 0; mt < 4; ++mt)
    #pragma unroll
    for (int gt = 0; gt < 4; ++gt)
      acc[mt][gt] = (f32x4){0.f, 0.f, 0.f, 0.f};

  __builtin_amdgcn_s_setprio(1);
  #pragma unroll 2
  for (int kb = 0; kb < KB; ++kb) {
    bf16x8 AH_[4], AL_[4];
    #pragma unroll
    for (int mt = 0; mt < 4; ++mt) {
      AH_[mt] = *(const bf16x8*)(At + swz((((mt)     * KB + kb) * 64 + lane) * 8));
      AL_[mt] = *(const bf16x8*)(At + swz((((4 + mt) * KB + kb) * 64 + lane) * 8));
    }
    bf16x8 BH[4], BL[4];
    #pragma unroll
    for (int gt = 0; gt < 4; ++gt) {
      BH[gt] = *(const bf16x8*)(bb  + ((long)kb * 32 + gt) * 512);
      BL[gt] = *(const bf16x8*)(blp + ((long)kb * 32 + gt) * 512);
    }
    #pragma unroll
    for (int gt = 0; gt < 4; ++gt) {
      #pragma unroll
      for (int mt = 0; mt < 4; ++mt) {
        acc[mt][gt] = __builtin_amdgcn_mfma_f32_16x16x32_bf16(AH_[mt], BH[gt], acc[mt][gt], 0, 0, 0);
        acc[mt][gt] = __builtin_amdgcn_mfma_f32_16x16x32_bf16(AL_[mt], BH[gt], acc[mt][gt], 0, 0, 0);
        acc[mt][gt] = __builtin_amdgcn_mfma_f32_16x16x32_bf16(AH_[mt], BL[gt], acc[mt][gt], 0, 0, 0);
      }
    }
  }
  __builtin_amdgcn_s_setprio(0);

  int f = w * 16 + l15;
  float bi = bias[f], bff = bias[128 + f], bo = bias[256 + f], bg = bias[384 + f];
  #pragma unroll
  for (int mt = 0; mt < 4; ++mt) {
    #pragma unroll
    for (int r = 0; r < 4; ++r) {
      int m = m0 + mt * 16 + lq * 4 + r;
      float vi = 1.0f / (1.0f + __expf(-(acc[mt][0][r] + bi)));
      float vf = 1.0f / (1.0f + __expf(-(acc[mt][1][r] + bff)));
      float vo = 1.0f / (1.0f + __expf(-(acc[mt][2][r] + bo)));
      float vg = tanhf(acc[mt][3][r] + bg);
      long idx = (long)m * H + f;
      float cn = vf * cbuf[idx] + vi * vg;
      float hn = vo * tanhf(cn);
      cbuf[idx] = cn;
      hout[idx] = (_Float16)hn;
      if (out2) {
        int bb2 = m >> 12, nn = m & (N_NODES - 1);
        __builtin_nontemporal_store(hn,
            &out2[(((long)bb2 * T + t) * N_NODES + nn) * H + f]);
      }
    }
  }
}

// ---------------- launch ----------------

extern "C" void kernel_launch(void* const* d_in, const int* in_sizes, int n_in,
                              void* d_out, int out_size, void* d_ws, size_t ws_size,
                              hipStream_t stream) {
  const float* x  = (const float*)d_in[0];
  const float* W0 = (const float*)d_in[1];
  const float* b0 = (const float*)d_in[2];
  const float* W1 = (const float*)d_in[3];
  const float* b1 = (const float*)d_in[4];
  const int*   ei = (const int*)d_in[5];
  const int* srcp = ei;
  const int* dstp = ei + N_EDGES;
  float* out = (float*)d_out;

  char* p = (char*)d_ws;
  auto alloc = [&](size_t bytes) {
    char* r = p;
    p += (bytes + 255) & ~(size_t)255;
    return r;
  };
  int*   cnt    = (int*)  alloc(N_NODES * 4);
  int*   fill   = (int*)  alloc(N_NODES * 4);
  float* dinv   = (float*)alloc(N_NODES * 4);
  int*   rowptr = (int*)  alloc((N_NODES + 1) * 4);
  int2*  eg     = (int2*) alloc((size_t)N_EDGES * 8);
  float* cc     = (float*)alloc((size_t)2 * M * H * 4);      // c0,c1 fp32
  _Float16* hh  = (_Float16*)alloc((size_t)4 * M * H * 2);   // h0 x2, h1 x2 (ping-pong)
  unsigned short* Bp0 = (unsigned short*)alloc((size_t)192 * 512 * 2 * 2);
  unsigned short* Bp1 = (unsigned short*)alloc((size_t)256 * 512 * 2 * 2);
  float*    c0  = cc;
  float*    c1  = cc + (size_t)M * H;
  _Float16* h0a = hh;
  _Float16* h0b = hh + (size_t)M * H;
  _Float16* h1a = hh + (size_t)2 * M * H;
  _Float16* h1b = hh + (size_t)3 * M * H;

  hipMemsetAsync(cnt,  0, N_NODES * 4, stream);
  hipMemsetAsync(fill, 0, N_NODES * 4, stream);
  hipMemsetAsync(cc,   0, (size_t)2 * M * H * 4, stream);
  hipMemsetAsync(hh,   0, (size_t)4 * M * H * 2, stream);

  k_count<<<N_EDGES / 256, 256, 0, stream>>>(dstp, cnt);
  k_dinv <<<N_NODES / 256, 256, 0, stream>>>(cnt, dinv);
  k_scan <<<1, 1024, 0, stream>>>(cnt, rowptr);
  k_fill <<<N_EDGES / 256, 256, 0, stream>>>(srcp, dstp, dinv, rowptr, fill, eg);
  k_pack <<<(192 * 64 + 255) / 256, 256, 0, stream>>>(W0, Bp0, 192);
  k_pack <<<(256 * 64 + 255) / 256, 256, 0, stream>>>(W1, Bp1, 256);

  for (int t = 0; t < T; ++t) {
    const _Float16* h0r = (t & 1) ? h0b : h0a;
    _Float16*       h0w = (t & 1) ? h0a : h0b;
    const _Float16* h1r = (t & 1) ? h1b : h1a;
    _Float16*       h1w = (t & 1) ? h1a : h1b;
    // layer 0: gather [x_t | h0_old] -> gates -> h0_new, c0
    k_fused<192, true><<<512, 512, 0, stream>>>(rowptr, eg, dinv,
        x + (size_t)t * N_NODES * D_INF, h0r, nullptr,
        Bp0, b0, h0w, c0, nullptr, t);
    // layer 1: gather [h0_new | h1_old] -> gates -> h1_new, c1, out
    k_fused<256, false><<<512, 512, 0, stream>>>(rowptr, eg, dinv,
        nullptr, h0w, h1r,
        Bp1, b1, h1w, c1, out, t);
  }
}

// Round 13
// 772.439 us; speedup vs baseline: 1.2842x; 1.0304x over previous
//
#include <hip/hip_runtime.h>
#include <hip/hip_fp16.h>
#include <math.h>

constexpr int N_NODES = 4096;
constexpr int N_EDGES = 65536;
constexpr int D_INF   = 64;
constexpr int H       = 128;
constexpr int T       = 8;
constexpr int B       = 8;
constexpr int M       = B * N_NODES;

typedef __attribute__((ext_vector_type(8))) short bf16x8;
typedef __attribute__((ext_vector_type(4))) float f32x4;
typedef __attribute__((ext_vector_type(8))) _Float16 f16x8;

__device__ inline unsigned short f2bf(float x) {
  unsigned int u = __float_as_uint(x);
  unsigned int r = (u + 0x7fffu + ((u >> 16) & 1u)) >> 16;
  return (unsigned short)r;
}
__device__ inline float bf2f(unsigned short b) {
  return __uint_as_float((unsigned int)b << 16);
}
// LDS bank swizzle: XOR short-index bits 7-9 into bits 3-5 (bank bits).
__device__ __forceinline__ int swz(int s) { return s ^ (((s >> 7) & 7) << 3); }

// ---------------- CSR build ----------------

__global__ void k_count(const int* __restrict__ dst, int* __restrict__ cnt) {
  int e = blockIdx.x * blockDim.x + threadIdx.x;
  if (e < N_EDGES) atomicAdd(&cnt[dst[e]], 1);
}

__global__ void k_dinv(const int* __restrict__ cnt, float* __restrict__ dinv) {
  int n = blockIdx.x * blockDim.x + threadIdx.x;
  if (n < N_NODES) dinv[n] = 1.0f / sqrtf((float)cnt[n] + 2.0f);
}

__global__ void k_scan(const int* __restrict__ cnt, int* __restrict__ rowptr) {
  __shared__ int sums[1024];
  int t = threadIdx.x;
  int v0 = cnt[4*t+0], v1 = cnt[4*t+1], v2 = cnt[4*t+2], v3 = cnt[4*t+3];
  int s0 = v0, s1 = s0 + v1, s2 = s1 + v2, s3 = s2 + v3;
  sums[t] = s3;
  __syncthreads();
  for (int off = 1; off < 1024; off <<= 1) {
    int x = (t >= off) ? sums[t - off] : 0;
    __syncthreads();
    sums[t] += x;
    __syncthreads();
  }
  int base = (t > 0) ? sums[t - 1] : 0;
  if (t == 0) rowptr[0] = 0;
  rowptr[4*t+1] = base + s0;
  rowptr[4*t+2] = base + s1;
  rowptr[4*t+3] = base + s2;
  rowptr[4*t+4] = base + s3;
}

__global__ void k_fill(const int* __restrict__ src, const int* __restrict__ dst,
                       const float* __restrict__ dinv, const int* __restrict__ rowptr,
                       int* __restrict__ fill, int2* __restrict__ eg) {
  int e = blockIdx.x * blockDim.x + threadIdx.x;
  if (e >= N_EDGES) return;
  int s = src[e], d = dst[e];
  int p = rowptr[d] + atomicAdd(&fill[d], 1);
  eg[p] = make_int2(s, __float_as_int(dinv[s] * dinv[d]));
}

// ---- degree counting sort: hist -> scan -> place (work balance, not output) ----
__global__ void k_hist(const int* __restrict__ cnt, int* __restrict__ hist) {
  int n = blockIdx.x * blockDim.x + threadIdx.x;
  if (n < N_NODES) atomicAdd(&hist[min(cnt[n], 127)], 1);
}

__global__ void k_hscan(const int* __restrict__ hist, int* __restrict__ hbase) {
  __shared__ int sh[128];
  int t = threadIdx.x;       // 128 threads
  sh[t] = hist[t];
  __syncthreads();
  for (int off = 1; off < 128; off <<= 1) {
    int x = (t >= off) ? sh[t - off] : 0;
    __syncthreads();
    sh[t] += x;
    __syncthreads();
  }
  hbase[t] = sh[t] - hist[t];   // exclusive
}

__global__ void k_place(const int* __restrict__ cnt, const int* __restrict__ hbase,
                        int* __restrict__ filld, int* __restrict__ sorted) {
  int n = blockIdx.x * blockDim.x + threadIdx.x;
  if (n >= N_NODES) return;
  int d = min(cnt[n], 127);
  sorted[hbase[d] + atomicAdd(&filld[d], 1)] = n;
}

// ---------------- W pack: gate-interleaved cols + MFMA fragment order + hi/lo ----
__global__ void k_pack(const float* __restrict__ W, unsigned short* __restrict__ Bp,
                       int K) {
  int tid = blockIdx.x * 256 + threadIdx.x;
  if (tid >= K * 64) return;
  int lane = tid & 63;
  int ntg  = (tid >> 6) & 31;
  int kb   = tid >> 11;
  int gate = ntg & 3, fg = ntg >> 2;
  int corig = gate * 128 + fg * 16 + (lane & 15);
  int k0 = kb * 32 + (lane >> 4) * 8;
  long obase = ((long)(kb * 32 + ntg) * 64 + lane) * 8;
  long plane = (long)K * 512;
  #pragma unroll
  for (int j = 0; j < 8; ++j) {
    float v = W[(long)(k0 + j) * 512 + corig];
    unsigned short h = f2bf(v);
    Bp[obase + j]         = h;
    Bp[plane + obase + j] = f2bf(v - bf2f(h));
  }
}

// ---------------- fused: gather -> swizzled LDS fragments -> MFMA -> LSTM ----
// Block = 8 waves (512 thr) = 64 node-rows x all 512 gate cols. 2 blocks/CU.
// DEGREE BALANCE: rows<->nodes via counting-sorted permutation; each 16-lane
// group handles pair (sorted[p], sorted[4095-p]) -> pair degree ~ 2*mean,
// so no group straggles at the barrier. Output bitwise identical.
template<int K, bool L0>
__global__ __launch_bounds__(512, 4) void k_fused(
    const int* __restrict__ rowptr, const int2* __restrict__ eg,
    const float* __restrict__ dinv, const int* __restrict__ sorted,
    const float* __restrict__ X32,      // L0 only: x_t base (batch stride T*N*D)
    const _Float16* __restrict__ PH0,   // L0: h0_old ; L1: h0_new
    const _Float16* __restrict__ PH1,   // L1: h1_old
    const unsigned short* __restrict__ Bp, const float* __restrict__ bias,
    _Float16* __restrict__ hout, float* __restrict__ cbuf,
    float* __restrict__ out2, int t) {
  constexpr int KB = K / 32;
  __shared__ __align__(16) unsigned short At[8 * KB * 64 * 8];  // 48/64 KB
  __shared__ int nodeLDS[64];
  int tid  = threadIdx.x;
  int lane = tid & 63;
  int w    = tid >> 6;                   // 0..7
  int j    = blockIdx.x;                 // 512 blocks (512%8==0, bijective)
  int b    = j & 7;                      // batch == XCD round-robin
  int jj   = j >> 3;                     // node-tile index within batch, 0..63
  int g    = lane >> 4, l = lane & 15;
  int c4   = l * 4, c8 = l * 8;

  // ---- phase 1: gather both planes, one balanced pair per 16-lane group ----
  const float*    Ax   = L0 ? (X32 + (long)b * ((long)T * N_NODES * D_INF)) : nullptr;
  const _Float16* Ah_p = L0 ? nullptr : (PH0 + (long)b * N_NODES * H);
  const _Float16* Bh_p = (L0 ? PH0 : PH1) + (long)b * N_NODES * H;
  constexpr int kbB0 = (L0 ? 64 : 128) >> 5;
  int lane2f = 16 * (l & 3);
  int kbB    = kbB0 + (c8 >> 5);
  int kbA16  = c8 >> 5;
  int kbA32  = c4 >> 5;
  int subA32 = (l & 7) >> 1;
  int j0A32  = (l & 1) * 4;

  #pragma unroll
  for (int nd = 0; nd < 2; ++nd) {
    int r  = (w << 3) + (g << 1) + nd;   // row in tile, 0..63
    int pairIdx = jj * 32 + (r >> 1);    // 0..2047
    int n  = (r & 1) ? sorted[N_NODES - 1 - pairIdx] : sorted[pairIdx];
    if (l == 0) nodeLDS[r] = n;
    int rs = rowptr[n], re = rowptr[n + 1];
    float accA[8] = {0.f,0.f,0.f,0.f,0.f,0.f,0.f,0.f};
    float accB[8] = {0.f,0.f,0.f,0.f,0.f,0.f,0.f,0.f};
    int e = rs;
    // 4-edge software pipeline: 4 metadata loads + 8 concurrent gathers
    for (; e + 3 < re; e += 4) {
      int2 q0 = eg[e], q1 = eg[e + 1], q2 = eg[e + 2], q3 = eg[e + 3];
      float w0 = __int_as_float(q0.y), w1 = __int_as_float(q1.y);
      float w2 = __int_as_float(q2.y), w3 = __int_as_float(q3.y);
      if constexpr (L0) {
        f32x4 a0 = *(const f32x4*)(Ax + (long)q0.x * D_INF + c4);
        f32x4 a1 = *(const f32x4*)(Ax + (long)q1.x * D_INF + c4);
        f32x4 a2 = *(const f32x4*)(Ax + (long)q2.x * D_INF + c4);
        f32x4 a3 = *(const f32x4*)(Ax + (long)q3.x * D_INF + c4);
        #pragma unroll
        for (int q = 0; q < 4; ++q)
          accA[q] += w0 * a0[q] + w1 * a1[q] + w2 * a2[q] + w3 * a3[q];
      } else {
        f16x8 a0 = *(const f16x8*)(Ah_p + (long)q0.x * H + c8);
        f16x8 a1 = *(const f16x8*)(Ah_p + (long)q1.x * H + c8);
        f16x8 a2 = *(const f16x8*)(Ah_p + (long)q2.x * H + c8);
        f16x8 a3 = *(const f16x8*)(Ah_p + (long)q3.x * H + c8);
        #pragma unroll
        for (int q = 0; q < 8; ++q)
          accA[q] += w0 * (float)a0[q] + w1 * (float)a1[q]
                   + w2 * (float)a2[q] + w3 * (float)a3[q];
      }
      f16x8 b0 = *(const f16x8*)(Bh_p + (long)q0.x * H + c8);
      f16x8 b1 = *(const f16x8*)(Bh_p + (long)q1.x * H + c8);
      f16x8 b2 = *(const f16x8*)(Bh_p + (long)q2.x * H + c8);
      f16x8 b3 = *(const f16x8*)(Bh_p + (long)q3.x * H + c8);
      #pragma unroll
      for (int q = 0; q < 8; ++q)
        accB[q] += w0 * (float)b0[q] + w1 * (float)b1[q]
                 + w2 * (float)b2[q] + w3 * (float)b3[q];
    }
    for (; e < re; ++e) {
      int2 q0 = eg[e];
      float w0 = __int_as_float(q0.y);
      if constexpr (L0) {
        f32x4 a0 = *(const f32x4*)(Ax + (long)q0.x * D_INF + c4);
        #pragma unroll
        for (int q = 0; q < 4; ++q) accA[q] += w0 * a0[q];
      } else {
        f16x8 a0 = *(const f16x8*)(Ah_p + (long)q0.x * H + c8);
        #pragma unroll
        for (int q = 0; q < 8; ++q) accA[q] += w0 * (float)a0[q];
      }
      f16x8 b0 = *(const f16x8*)(Bh_p + (long)q0.x * H + c8);
      #pragma unroll
      for (int q = 0; q < 8; ++q) accB[q] += w0 * (float)b0[q];
    }
    float dn = dinv[n];
    float sw = 2.0f * dn * dn;
    if constexpr (L0) {
      f32x4 a = *(const f32x4*)(Ax + (long)n * D_INF + c4);
      #pragma unroll
      for (int q = 0; q < 4; ++q) accA[q] += sw * a[q];
    } else {
      f16x8 a = *(const f16x8*)(Ah_p + (long)n * H + c8);
      #pragma unroll
      for (int q = 0; q < 8; ++q) accA[q] += sw * (float)a[q];
    }
    {
      f16x8 v = *(const f16x8*)(Bh_p + (long)n * H + c8);
      #pragma unroll
      for (int q = 0; q < 8; ++q) accB[q] += sw * (float)v[q];
    }

    int mt    = r >> 4;                  // 0..3
    int lane2 = (r & 15) + lane2f;
    // plane B: full 8-feat chunk (hi pm=mt, lo pm=4+mt)
    {
      bf16x8 hv, lv;
      #pragma unroll
      for (int q = 0; q < 8; ++q) {
        unsigned short hs = f2bf(accB[q]);
        hv[q] = (short)hs;
        lv[q] = (short)f2bf(accB[q] - bf2f(hs));
      }
      *(bf16x8*)(At + swz((((mt)     * KB + kbB) * 64 + lane2) * 8)) = hv;
      *(bf16x8*)(At + swz((((4 + mt) * KB + kbB) * 64 + lane2) * 8)) = lv;
    }
    // plane A
    if constexpr (L0) {
      unsigned long long hv = 0ull, lv = 0ull;
      #pragma unroll
      for (int q = 0; q < 4; ++q) {
        unsigned short hs = f2bf(accA[q]);
        unsigned short ls = f2bf(accA[q] - bf2f(hs));
        hv |= (unsigned long long)hs << (16 * q);
        lv |= (unsigned long long)ls << (16 * q);
      }
      int lA = (r & 15) + 16 * subA32;
      *(unsigned long long*)(At + swz((((mt)     * KB + kbA32) * 64 + lA) * 8 + j0A32)) = hv;
      *(unsigned long long*)(At + swz((((4 + mt) * KB + kbA32) * 64 + lA) * 8 + j0A32)) = lv;
    } else {
      bf16x8 hv, lv;
      #pragma unroll
      for (int q = 0; q < 8; ++q) {
        unsigned short hs = f2bf(accA[q]);
        hv[q] = (short)hs;
        lv[q] = (short)f2bf(accA[q] - bf2f(hs));
      }
      *(bf16x8*)(At + swz((((mt)     * KB + kbA16) * 64 + lane2) * 8)) = hv;
      *(bf16x8*)(At + swz((((4 + mt) * KB + kbA16) * 64 + lane2) * 8)) = lv;
    }
  }
  __syncthreads();

  // ---- phase 2: split-bf16 3-term MFMA + LSTM epilogue (1 fg per wave) ----
  int l15 = lane & 15, lq = lane >> 4;
  const unsigned short* bb  = Bp + (long)(w * 4) * 512 + lane * 8;
  const unsigned short* blp = bb + (long)K * 512;

  f32x4 acc[4][4];
  #pragma unroll
  for (int mt = 0; mt < 4; ++mt)
    #pragma unroll
    for (int gt = 0; gt < 4; ++gt)
      acc[mt][gt] = (f32x4){0.f, 0.f, 0.f, 0.f};

  __builtin_amdgcn_s_setprio(1);
  #pragma unroll 2
  for (int kb = 0; kb < KB; ++kb) {
    bf16x8 AH_[4], AL_[4];
    #pragma unroll
    for (int mt = 0; mt < 4; ++mt) {
      AH_[mt] = *(const bf16x8*)(At + swz((((mt)     * KB + kb) * 64 + lane) * 8));
      AL_[mt] = *(const bf16x8*)(At + swz((((4 + mt) * KB + kb) * 64 + lane) * 8));
    }
    bf16x8 BH[4], BL[4];
    #pragma unroll
    for (int gt = 0; gt < 4; ++gt) {
      BH[gt] = *(const bf16x8*)(bb  + ((long)kb * 32 + gt) * 512);
      BL[gt] = *(const bf16x8*)(blp + ((long)kb * 32 + gt) * 512);
    }
    #pragma unroll
    for (int gt = 0; gt < 4; ++gt) {
      #pragma unroll
      for (int mt = 0; mt < 4; ++mt) {
        acc[mt][gt] = __builtin_amdgcn_mfma_f32_16x16x32_bf16(AH_[mt], BH[gt], acc[mt][gt], 0, 0, 0);
        acc[mt][gt] = __builtin_amdgcn_mfma_f32_16x16x32_bf16(AL_[mt], BH[gt], acc[mt][gt], 0, 0, 0);
        acc[mt][gt] = __builtin_amdgcn_mfma_f32_16x16x32_bf16(AH_[mt], BL[gt], acc[mt][gt], 0, 0, 0);
      }
    }
  }
  __builtin_amdgcn_s_setprio(0);

  int f = w * 16 + l15;
  float bi = bias[f], bff = bias[128 + f], bo = bias[256 + f], bg = bias[384 + f];
  #pragma unroll
  for (int mt = 0; mt < 4; ++mt) {
    #pragma unroll
    for (int r = 0; r < 4; ++r) {
      int rt = mt * 16 + lq * 4 + r;     // row in tile
      int n2 = nodeLDS[rt];
      float vi = 1.0f / (1.0f + __expf(-(acc[mt][0][r] + bi)));
      float vf = 1.0f / (1.0f + __expf(-(acc[mt][1][r] + bff)));
      float vo = 1.0f / (1.0f + __expf(-(acc[mt][2][r] + bo)));
      float vg = tanhf(acc[mt][3][r] + bg);
      long idx = ((long)b * N_NODES + n2) * H + f;
      float cn = vf * cbuf[idx] + vi * vg;
      float hn = vo * tanhf(cn);
      cbuf[idx] = cn;
      hout[idx] = (_Float16)hn;
      if (out2) {
        __builtin_nontemporal_store(hn,
            &out2[(((long)b * T + t) * N_NODES + n2) * H + f]);
      }
    }
  }
}

// ---------------- launch ----------------

extern "C" void kernel_launch(void* const* d_in, const int* in_sizes, int n_in,
                              void* d_out, int out_size, void* d_ws, size_t ws_size,
                              hipStream_t stream) {
  const float* x  = (const float*)d_in[0];
  const float* W0 = (const float*)d_in[1];
  const float* b0 = (const float*)d_in[2];
  const float* W1 = (const float*)d_in[3];
  const float* b1 = (const float*)d_in[4];
  const int*   ei = (const int*)d_in[5];
  const int* srcp = ei;
  const int* dstp = ei + N_EDGES;
  float* out = (float*)d_out;

  char* p = (char*)d_ws;
  auto alloc = [&](size_t bytes) {
    char* r = p;
    p += (bytes + 255) & ~(size_t)255;
    return r;
  };
  int*   cnt    = (int*)  alloc(N_NODES * 4);
  int*   fill   = (int*)  alloc(N_NODES * 4);
  float* dinv   = (float*)alloc(N_NODES * 4);
  int*   rowptr = (int*)  alloc((N_NODES + 1) * 4);
  int2*  eg     = (int2*) alloc((size_t)N_EDGES * 8);
  int*   hist   = (int*)  alloc(128 * 4);
  int*   hbase  = (int*)  alloc(128 * 4);
  int*   filld  = (int*)  alloc(128 * 4);
  int*   sorted = (int*)  alloc(N_NODES * 4);
  float* cc     = (float*)alloc((size_t)2 * M * H * 4);      // c0,c1 fp32
  _Float16* hh  = (_Float16*)alloc((size_t)4 * M * H * 2);   // h0 x2, h1 x2 (ping-pong)
  unsigned short* Bp0 = (unsigned short*)alloc((size_t)192 * 512 * 2 * 2);
  unsigned short* Bp1 = (unsigned short*)alloc((size_t)256 * 512 * 2 * 2);
  float*    c0  = cc;
  float*    c1  = cc + (size_t)M * H;
  _Float16* h0a = hh;
  _Float16* h0b = hh + (size_t)M * H;
  _Float16* h1a = hh + (size_t)2 * M * H;
  _Float16* h1b = hh + (size_t)3 * M * H;

  hipMemsetAsync(cnt,   0, N_NODES * 4, stream);
  hipMemsetAsync(fill,  0, N_NODES * 4, stream);
  hipMemsetAsync(hist,  0, 128 * 4, stream);
  hipMemsetAsync(filld, 0, 128 * 4, stream);
  hipMemsetAsync(cc,    0, (size_t)2 * M * H * 4, stream);
  hipMemsetAsync(hh,    0, (size_t)4 * M * H * 2, stream);

  k_count<<<N_EDGES / 256, 256, 0, stream>>>(dstp, cnt);
  k_dinv <<<N_NODES / 256, 256, 0, stream>>>(cnt, dinv);
  k_scan <<<1, 1024, 0, stream>>>(cnt, rowptr);
  k_fill <<<N_EDGES / 256, 256, 0, stream>>>(srcp, dstp, dinv, rowptr, fill, eg);
  k_hist <<<N_NODES / 256, 256, 0, stream>>>(cnt, hist);
  k_hscan<<<1, 128, 0, stream>>>(hist, hbase);
  k_place<<<N_NODES / 256, 256, 0, stream>>>(cnt, hbase, filld, sorted);
  k_pack <<<(192 * 64 + 255) / 256, 256, 0, stream>>>(W0, Bp0, 192);
  k_pack <<<(256 * 64 + 255) / 256, 256, 0, stream>>>(W1, Bp1, 256);

  for (int t = 0; t < T; ++t) {
    const _Float16* h0r = (t & 1) ? h0b : h0a;
    _Float16*       h0w = (t & 1) ? h0a : h0b;
    const _Float16* h1r = (t & 1) ? h1b : h1a;
    _Float16*       h1w = (t & 1) ? h1a : h1b;
    // layer 0: gather [x_t | h0_old] -> gates -> h0_new, c0
    k_fused<192, true><<<512, 512, 0, stream>>>(rowptr, eg, dinv, sorted,
        x + (size_t)t * N_NODES * D_INF, h0r, nullptr,
        Bp0, b0, h0w, c0, nullptr, t);
    // layer 1: gather [h0_new | h1_old] -> gates -> h1_new, c1, out
    k_fused<256, false><<<512, 512, 0, stream>>>(rowptr, eg, dinv, sorted,
        nullptr, h0w, h1r,
        Bp1, b1, h1w, c1, out, t);
  }
}